// Round 2
// baseline (1718.199 us; speedup 1.0000x reference)
//
#include <hip/hip_runtime.h>
#include <stdint.h>

#define CDIM   256
#define NPIX   65536
#define NBATCH 8
#define KTHRESH 0.01

// workspace layout (float indices)
#define WS_DELTA 0        // 256 floats: normalize(c1)-normalize(c0)
#define WS_CENT  256      // 512 floats: current raw centers [K][C]
#define WS_T     768      // 2048 floats: per-batch totals  T[b][c]
#define WS_S1    2816     // 2048 floats: per-batch label-1 sums S1[b][c]
#define WS_CNT   4864     // 8 uints: per-batch label-1 counts
#define WS_DONE  4872     // 1 int: convergence flag
#define WS_FT    8192     // FT[b][n][c] fp32, 8*65536*256*4 B = 537 MB (ws is 2 GB)

// output layout (floats): centers[2*256] | labels[8*65536] | onehot[8*65536*2] | cur_dist
#define OUT_LABELS 512
#define OUT_ONEHOT (512 + NBATCH * NPIX)
#define OUT_CDIST  (512 + NBATCH * NPIX + 2 * NBATCH * NPIX)

__device__ __forceinline__ double block_reduce(double v, double* sh) {
  const int t = threadIdx.x;
  #pragma unroll
  for (int off = 32; off > 0; off >>= 1) v += __shfl_down(v, off, 64);
  __syncthreads();
  if ((t & 63) == 0) sh[t >> 6] = v;
  __syncthreads();
  return sh[0] + sh[1] + sh[2] + sh[3];
}

__device__ __forceinline__ void block_reduce4(double v[4], double* sh) {
  const int t = threadIdx.x;
  #pragma unroll
  for (int off = 32; off > 0; off >>= 1) {
    v[0] += __shfl_down(v[0], off, 64);
    v[1] += __shfl_down(v[1], off, 64);
    v[2] += __shfl_down(v[2], off, 64);
    v[3] += __shfl_down(v[3], off, 64);
  }
  __syncthreads();
  if ((t & 63) == 0) {
    const int w = t >> 6;
    sh[w] = v[0]; sh[4 + w] = v[1]; sh[8 + w] = v[2]; sh[12 + w] = v[3];
  }
  __syncthreads();
  #pragma unroll
  for (int k = 0; k < 4; ++k) v[k] = sh[4 * k] + sh[4 * k + 1] + sh[4 * k + 2] + sh[4 * k + 3];
}

__global__ __launch_bounds__(256) void init_kernel(const float* __restrict__ cinit,
                                                   float* __restrict__ ws) {
  __shared__ double sh[16];
  const int t = threadIdx.x;
  for (int i = t; i < NBATCH * CDIM; i += 256) { ws[WS_T + i] = 0.f; ws[WS_S1 + i] = 0.f; }
  if (t < NBATCH) ((unsigned int*)(ws + WS_CNT))[t] = 0u;
  if (t == 0) ((int*)(ws + WS_DONE))[0] = 0;
  const float c0f = cinit[t], c1f = cinit[CDIM + t];
  ws[WS_CENT + t] = c0f;
  ws[WS_CENT + CDIM + t] = c1f;
  const double c0 = (double)c0f, c1 = (double)c1f;
  double n0 = sqrt(block_reduce(c0 * c0, sh));
  double n1 = sqrt(block_reduce(c1 * c1, sh));
  n0 = fmax(n0, 1e-12); n1 = fmax(n1, 1e-12);
  ws[WS_DELTA + t] = (float)(c1 / n1) - (float)(c0 / n0);
}

// One-time transpose F[b][c][n] -> FT[b][n][c], plus mask-independent totals T[b][c].
// Tile: 64 c-rows x 256 n. Read: 64 x 1KB contiguous. Write: 256 x 256B contiguous.
// LDS row stride 257 floats: read-back bank = (l + n) % 32 -> conflict-free.
__global__ __launch_bounds__(256, 2) void transpose_kernel(const float* __restrict__ F,
                                                           float* __restrict__ ws) {
  __shared__ float tile[64 * 257];
  const int t = threadIdx.x, w = t >> 6, l = t & 63;
  const int bid  = blockIdx.x;
  const int b    = bid >> 10;            // 1024 tiles per batch
  const int cblk = (bid >> 8) & 3;       // 4 c-blocks of 64
  const int nblk = bid & 255;            // 256 n-blocks of 256
  const int c0 = cblk * 64;
  const size_t n0 = (size_t)nblk * 256;

  const float* Fb = F + ((size_t)b * CDIM + c0) * NPIX + n0;

  #pragma unroll
  for (int i = 0; i < 16; ++i) {
    const int r = w * 16 + i;                       // c-row within tile
    const float4 v = ((const float4*)(Fb + (size_t)r * NPIX))[l];
    float* rowp = tile + r * 257 + 4 * l;
    rowp[0] = v.x; rowp[1] = v.y; rowp[2] = v.z; rowp[3] = v.w;
    float p = (v.x + v.y) + (v.z + v.w);            // totals partial (once, iter-free)
    #pragma unroll
    for (int off = 32; off > 0; off >>= 1) p += __shfl_down(p, off, 64);
    if (l == 0) unsafeAtomicAdd(&ws[WS_T + b * CDIM + c0 + r], p);
  }
  __syncthreads();

  float* FTp = ws + WS_FT + ((size_t)b * NPIX + n0) * CDIM + c0;
  #pragma unroll 8
  for (int i = 0; i < 64; ++i) {
    const int n = w * 64 + i;
    FTp[(size_t)n * CDIM + l] = tile[l * 257 + n];  // 64 lanes x 4B contiguous
  }
}

// Single linear sweep over FT per iteration. 2048 blocks, 256 columns each.
// 8 lanes per column (octant o = l&7): per instr 8 lanes read 128B contiguous.
// Full fp64 column dot via 3 shfl_xor; masked sums accumulate in registers
// (lane's c-set fixed: c = 32j + 4o + e), one butterfly + one atomic per (b,c).
__global__ __launch_bounds__(256, 4) void pass_kernel(float* __restrict__ ws,
                                                      float* __restrict__ out,
                                                      int iter) {
  if (iter > 0 && ((const volatile int*)(ws + WS_DONE))[0] != 0) return;

  __shared__ float deltaS[CDIM];
  __shared__ float s1sh[4 * CDIM];
  __shared__ unsigned cntS;

  const int t = threadIdx.x, w = t >> 6, l = t & 63;
  const int o  = l & 7;                      // c-octant within column
  const int cq = l >> 3;                     // column within wave's 8
  const int b  = blockIdx.x >> 8;            // 256 blocks per batch
  const int n0 = (blockIdx.x & 255) * 256;

  deltaS[t] = ws[WS_DELTA + t];
  if (t == 0) cntS = 0u;
  __syncthreads();

  const float* FTb = ws + WS_FT + (size_t)b * NPIX * CDIM;

  float4 macc[8];
  #pragma unroll
  for (int j = 0; j < 8; ++j) macc[j] = make_float4(0.f, 0.f, 0.f, 0.f);
  unsigned cnt = 0;

  for (int g = 0; g < 8; ++g) {              // 32 columns per group (8 per wave)
    const int n = n0 + g * 32 + w * 8 + cq;
    const float4* colp = (const float4*)(FTb + (size_t)n * CDIM);
    float4 v[8];
    #pragma unroll
    for (int j = 0; j < 8; ++j) v[j] = colp[8 * j + o];

    double d = 0.0;
    #pragma unroll
    for (int j = 0; j < 8; ++j) {
      const float4 dl = ((const float4*)deltaS)[8 * j + o];   // broadcast per o
      d = fma((double)dl.x, (double)v[j].x, d);
      d = fma((double)dl.y, (double)v[j].y, d);
      d = fma((double)dl.z, (double)v[j].z, d);
      d = fma((double)dl.w, (double)v[j].w, d);
    }
    d += __shfl_xor(d, 1, 64);
    d += __shfl_xor(d, 2, 64);
    d += __shfl_xor(d, 4, 64);               // all 8 lanes hold full dot

    const unsigned long long ball = __ballot(d > 0.0);
    cnt += (unsigned)__popcll(ball & 0x0101010101010101ull);

    const float m = d > 0.0 ? 1.f : 0.f;
    if (o == 0) {
      const int gi = b * NPIX + n;
      out[OUT_LABELS + gi] = m;
      ((float2*)(out + OUT_ONEHOT))[gi] = make_float2(1.f - m, m);
    }
    #pragma unroll
    for (int j = 0; j < 8; ++j) {
      macc[j].x = fmaf(m, v[j].x, macc[j].x);
      macc[j].y = fmaf(m, v[j].y, macc[j].y);
      macc[j].z = fmaf(m, v[j].z, macc[j].z);
      macc[j].w = fmaf(m, v[j].w, macc[j].w);
    }
  }

  // reduce across the 8 column-octets (lanes sharing o)
  #pragma unroll
  for (int s = 8; s < 64; s <<= 1) {
    #pragma unroll
    for (int j = 0; j < 8; ++j) {
      macc[j].x += __shfl_xor(macc[j].x, s, 64);
      macc[j].y += __shfl_xor(macc[j].y, s, 64);
      macc[j].z += __shfl_xor(macc[j].z, s, 64);
      macc[j].w += __shfl_xor(macc[j].w, s, 64);
    }
  }
  if (l < 8) {
    #pragma unroll
    for (int j = 0; j < 8; ++j)
      ((float4*)(s1sh + w * CDIM))[8 * j + l] = macc[j];
  }
  if (l == 0) atomicAdd(&cntS, cnt);
  __syncthreads();

  const float s = (s1sh[t] + s1sh[CDIM + t]) + (s1sh[2 * CDIM + t] + s1sh[3 * CDIM + t]);
  unsafeAtomicAdd(&ws[WS_S1 + b * CDIM + t], s);
  if (t == 0) atomicAdd(&((unsigned int*)(ws + WS_CNT))[b], cntS);
}

__global__ __launch_bounds__(256) void finalize_kernel(float* __restrict__ ws,
                                                       float* __restrict__ out) {
  __shared__ double sh[16];
  const int t = threadIdx.x;
  if (((const volatile int*)(ws + WS_DONE))[0] != 0) return;  // frozen: keep prior outputs

  const double cold0 = (double)ws[WS_CENT + t];
  const double cold1 = (double)ws[WS_CENT + CDIM + t];
  const double normc0 = sqrt(block_reduce(cold0 * cold0, sh));
  const double normc1 = sqrt(block_reduce(cold1 * cold1, sh));

  double acc0 = 0.0, acc1 = 0.0, cdsum = 0.0;
  for (int b = 0; b < NBATCH; ++b) {
    const double s1v  = (double)ws[WS_S1 + b * CDIM + t];
    const double totv = (double)ws[WS_T  + b * CDIM + t];
    const double c1n  = (double)((unsigned int*)(ws + WS_CNT))[b];
    const double ci1  = s1v / (c1n + 1.0);
    const double ci0  = (totv - s1v) / ((double)NPIX - c1n + 1.0);
    acc0 += ci0; acc1 += ci1;
    double v[4] = {ci0 * cold0, ci0 * ci0, ci1 * cold1, ci1 * ci1};
    block_reduce4(v, sh);
    const double den0 = fmax(sqrt(v[1]) * normc0, 1e-8);
    const double den1 = fmax(sqrt(v[3]) * normc1, 1e-8);
    cdsum += 0.5 * (v[0] / den0 + v[2] / den1);
  }
  const double curdist = cdsum / (double)NBATCH;
  const float nc0f = (float)(acc0 / (double)NBATCH);
  const float nc1f = (float)(acc1 / (double)NBATCH);

  ws[WS_CENT + t] = nc0f;
  ws[WS_CENT + CDIM + t] = nc1f;
  out[t] = nc0f;
  out[CDIM + t] = nc1f;
  if (t == 0) out[OUT_CDIST] = (float)curdist;

  double m0 = sqrt(block_reduce((double)nc0f * (double)nc0f, sh));
  double m1 = sqrt(block_reduce((double)nc1f * (double)nc1f, sh));
  m0 = fmax(m0, 1e-12); m1 = fmax(m1, 1e-12);
  ws[WS_DELTA + t] = (float)((double)nc1f / m1) - (float)((double)nc0f / m0);

  __syncthreads();
  for (int i = t; i < NBATCH * CDIM; i += 256) ws[WS_S1 + i] = 0.f;
  if (t < NBATCH) ((unsigned int*)(ws + WS_CNT))[t] = 0u;
  if (t == 0) ((int*)(ws + WS_DONE))[0] = (curdist < KTHRESH) ? 1 : 0;
}

extern "C" void kernel_launch(void* const* d_in, const int* in_sizes, int n_in,
                              void* d_out, int out_size, void* d_ws, size_t ws_size,
                              hipStream_t stream) {
  const float* F     = (const float*)d_in[0];
  const float* cinit = (const float*)d_in[1];
  float* out = (float*)d_out;
  float* ws  = (float*)d_ws;

  init_kernel<<<1, 256, 0, stream>>>(cinit, ws);
  transpose_kernel<<<NBATCH * 4 * 256, 256, 0, stream>>>(F, ws);
  for (int iter = 0; iter < 3; ++iter) {
    pass_kernel<<<NBATCH * 256, 256, 0, stream>>>(ws, out, iter);
    finalize_kernel<<<1, 256, 0, stream>>>(ws, out);
  }
}

// Round 3
// 1395.263 us; speedup vs baseline: 1.2315x; 1.2315x over previous
//
#include <hip/hip_runtime.h>
#include <stdint.h>

#define CDIM   256
#define NPIX   65536
#define NBATCH 8
#define KTHRESH 0.01

// workspace layout (float indices)
#define WS_DELTA 0        // 256 floats: normalize(c1)-normalize(c0)
#define WS_CENT  256      // 512 floats: current raw centers [K][C]
#define WS_T     768      // 2048 floats: per-batch totals  T[b][c]
#define WS_S1    2816     // 2048 floats: per-batch label-1 sums S1[b][c]
#define WS_CNT   4864     // 8 uints: per-batch label-1 counts
#define WS_DONE  4872     // 1 int: convergence flag

// output layout (floats): centers[2*256] | labels[8*65536] | onehot[8*65536*2] | cur_dist
#define OUT_LABELS 512
#define OUT_ONEHOT (512 + NBATCH * NPIX)
#define OUT_CDIST  (512 + NBATCH * NPIX + 2 * NBATCH * NPIX)

__device__ __forceinline__ double block_reduce(double v, double* sh) {
  const int t = threadIdx.x;
  #pragma unroll
  for (int off = 32; off > 0; off >>= 1) v += __shfl_down(v, off, 64);
  __syncthreads();
  if ((t & 63) == 0) sh[t >> 6] = v;
  __syncthreads();
  return sh[0] + sh[1] + sh[2] + sh[3];
}

__device__ __forceinline__ double wave_reduce(double v) {
  #pragma unroll
  for (int off = 32; off > 0; off >>= 1) v += __shfl_xor(v, off, 64);
  return v;
}

__global__ __launch_bounds__(256) void init_kernel(const float* __restrict__ cinit,
                                                   float* __restrict__ ws) {
  __shared__ double sh[16];
  const int t = threadIdx.x;
  for (int i = t; i < NBATCH * CDIM; i += 256) { ws[WS_T + i] = 0.f; ws[WS_S1 + i] = 0.f; }
  if (t < NBATCH) ((unsigned int*)(ws + WS_CNT))[t] = 0u;
  if (t == 0) ((int*)(ws + WS_DONE))[0] = 0;
  const float c0f = cinit[t], c1f = cinit[CDIM + t];
  ws[WS_CENT + t] = c0f;
  ws[WS_CENT + CDIM + t] = c1f;
  const double c0 = (double)c0f, c1 = (double)c1f;
  double n0 = sqrt(block_reduce(c0 * c0, sh));
  double n1 = sqrt(block_reduce(c1 * c1, sh));
  n0 = fmax(n0, 1e-12); n1 = fmax(n1, 1e-12);
  ws[WS_DELTA + t] = (float)(c1 / n1) - (float)(c0 / n0);
}

// 2048 blocks x 256 threads; block = (batch b, 256-column slice n0).
// Phase A: thread t owns column n0+t. 32-deep scalar load bursts (wave-instr =
//   256B contiguous) into a register array BEFORE the fp64 dot consumes them ->
//   deep memory-level parallelism. Labels via sign of dot(delta, x).
// Phase B: thread t owns channel t; sweeps the block's 256 columns (1KB/thread,
//   L1/L2-hot from phase A) with broadcast LDS labels; 1 atomic per (b,c)/block.
__global__ __launch_bounds__(256, 4) void pass_kernel(const float* __restrict__ F,
                                                      float* __restrict__ ws,
                                                      float* __restrict__ out,
                                                      int iter) {
  if (iter > 0 && ((const volatile int*)(ws + WS_DONE))[0] != 0) return;

  __shared__ double deltaD[CDIM];
  __shared__ float mlab[CDIM];
  __shared__ unsigned cntS;

  const int t = threadIdx.x, l = t & 63;
  const int b  = blockIdx.x >> 8;            // 256 blocks per batch
  const int n0 = (blockIdx.x & 255) * 256;

  deltaD[t] = (double)ws[WS_DELTA + t];
  if (t == 0) cntS = 0u;
  __syncthreads();

  const float* __restrict__ Fb = F + (size_t)b * CDIM * NPIX;

  // ---- phase A ----
  double a0 = 0.0, a1 = 0.0, a2 = 0.0, a3 = 0.0;
  {
    const float* __restrict__ p = Fb + n0 + t;
    for (int cc = 0; cc < CDIM; cc += 32) {
      float v[32];
      #pragma unroll
      for (int j = 0; j < 32; ++j) v[j] = p[(size_t)(cc + j) * NPIX];
      #pragma unroll
      for (int j = 0; j < 32; j += 4) {
        a0 = fma(deltaD[cc + j + 0], (double)v[j + 0], a0);
        a1 = fma(deltaD[cc + j + 1], (double)v[j + 1], a1);
        a2 = fma(deltaD[cc + j + 2], (double)v[j + 2], a2);
        a3 = fma(deltaD[cc + j + 3], (double)v[j + 3], a3);
      }
    }
  }
  const double d = (a0 + a1) + (a2 + a3);
  const float m = d > 0.0 ? 1.f : 0.f;
  mlab[t] = m;
  const unsigned long long ball = __ballot(d > 0.0);
  if (l == 0) atomicAdd(&cntS, (unsigned)__popcll(ball));

  const int gi = b * NPIX + n0 + t;
  out[OUT_LABELS + gi] = m;
  ((float2*)(out + OUT_ONEHOT))[gi] = make_float2(1.f - m, m);
  __syncthreads();

  // ---- phase B ----
  float s1 = 0.f, tot = 0.f;
  const float4* __restrict__ rp = (const float4*)(Fb + (size_t)t * NPIX + n0);
  const float4* __restrict__ ml4 = (const float4*)mlab;
  for (int q = 0; q < 64; q += 8) {
    float4 v[8];
    #pragma unroll
    for (int j = 0; j < 8; ++j) v[j] = rp[q + j];
    #pragma unroll
    for (int j = 0; j < 8; ++j) {
      const float4 mm = ml4[q + j];          // LDS broadcast (uniform addr)
      s1 = fmaf(mm.x, v[j].x, s1);
      s1 = fmaf(mm.y, v[j].y, s1);
      s1 = fmaf(mm.z, v[j].z, s1);
      s1 = fmaf(mm.w, v[j].w, s1);
      tot += (v[j].x + v[j].y) + (v[j].z + v[j].w);
    }
  }
  unsafeAtomicAdd(&ws[WS_S1 + b * CDIM + t], s1);
  if (iter == 0) unsafeAtomicAdd(&ws[WS_T + b * CDIM + t], tot);
  if (t == 0) atomicAdd(&((unsigned int*)(ws + WS_CNT))[b], cntS);
}

// 512 threads: wave w handles batch b=w (shuffle-only per-batch reductions).
__global__ __launch_bounds__(512) void finalize_kernel(float* __restrict__ ws,
                                                       float* __restrict__ out) {
  if (((const volatile int*)(ws + WS_DONE))[0] != 0) return;  // frozen: keep prior outputs

  __shared__ double ci0sh[NBATCH][CDIM];
  __shared__ double ci1sh[NBATCH][CDIM];
  __shared__ double cdsh[NBATCH];
  __shared__ double sh2[16];

  const int t = threadIdx.x, w = t >> 6, l = t & 63;
  const int b = w;

  // cold-center norms (per-wave redundant compute, no barriers)
  double c0k[4], c1k[4], p0 = 0.0, p1 = 0.0;
  #pragma unroll
  for (int k = 0; k < 4; ++k) {
    const int c = l + 64 * k;
    c0k[k] = (double)ws[WS_CENT + c];
    c1k[k] = (double)ws[WS_CENT + CDIM + c];
    p0 += c0k[k] * c0k[k];
    p1 += c1k[k] * c1k[k];
  }
  const double normc0 = sqrt(wave_reduce(p0));
  const double normc1 = sqrt(wave_reduce(p1));

  const double c1n = (double)((unsigned int*)(ws + WS_CNT))[b];
  double v0 = 0.0, v1 = 0.0, v2 = 0.0, v3 = 0.0;
  #pragma unroll
  for (int k = 0; k < 4; ++k) {
    const int c = l + 64 * k;
    const double s1v  = (double)ws[WS_S1 + b * CDIM + c];
    const double totv = (double)ws[WS_T  + b * CDIM + c];
    const double ci1 = s1v / (c1n + 1.0);
    const double ci0 = (totv - s1v) / ((double)NPIX - c1n + 1.0);
    ci0sh[b][c] = ci0; ci1sh[b][c] = ci1;
    v0 += ci0 * c0k[k]; v1 += ci0 * ci0;
    v2 += ci1 * c1k[k]; v3 += ci1 * ci1;
  }
  v0 = wave_reduce(v0); v1 = wave_reduce(v1);
  v2 = wave_reduce(v2); v3 = wave_reduce(v3);
  if (l == 0) {
    const double den0 = fmax(sqrt(v1) * normc0, 1e-8);
    const double den1 = fmax(sqrt(v3) * normc1, 1e-8);
    cdsh[b] = 0.5 * (v0 / den0 + v2 / den1);
  }
  __syncthreads();

  float nc0f = 0.f, nc1f = 0.f;
  if (t < CDIM) {
    double a0 = 0.0, a1 = 0.0;
    #pragma unroll
    for (int bb = 0; bb < NBATCH; ++bb) { a0 += ci0sh[bb][t]; a1 += ci1sh[bb][t]; }
    nc0f = (float)(a0 / (double)NBATCH);
    nc1f = (float)(a1 / (double)NBATCH);
    ws[WS_CENT + t] = nc0f;
    ws[WS_CENT + CDIM + t] = nc1f;
    out[t] = nc0f; out[CDIM + t] = nc1f;
  }
  double curdist = 0.0;
  if (t == 0) {
    #pragma unroll
    for (int bb = 0; bb < NBATCH; ++bb) curdist += cdsh[bb];
    curdist /= (double)NBATCH;
    out[OUT_CDIST] = (float)curdist;
  }

  // norms of new centers -> delta for next iter (waves 4..7 contribute zero)
  double q0 = (t < CDIM) ? (double)nc0f * (double)nc0f : 0.0;
  double q1 = (t < CDIM) ? (double)nc1f * (double)nc1f : 0.0;
  q0 = wave_reduce(q0); q1 = wave_reduce(q1);
  if (l == 0) { sh2[w] = q0; sh2[8 + w] = q1; }
  __syncthreads();
  double m0 = 0.0, m1 = 0.0;
  #pragma unroll
  for (int k = 0; k < 8; ++k) { m0 += sh2[k]; m1 += sh2[8 + k]; }
  m0 = fmax(sqrt(m0), 1e-12); m1 = fmax(sqrt(m1), 1e-12);
  if (t < CDIM)
    ws[WS_DELTA + t] = (float)((double)nc1f / m1) - (float)((double)nc0f / m0);

  for (int i = t; i < NBATCH * CDIM; i += 512) ws[WS_S1 + i] = 0.f;
  if (t < NBATCH) ((unsigned int*)(ws + WS_CNT))[t] = 0u;
  if (t == 0) ((int*)(ws + WS_DONE))[0] = (curdist < KTHRESH) ? 1 : 0;
}

extern "C" void kernel_launch(void* const* d_in, const int* in_sizes, int n_in,
                              void* d_out, int out_size, void* d_ws, size_t ws_size,
                              hipStream_t stream) {
  const float* F     = (const float*)d_in[0];
  const float* cinit = (const float*)d_in[1];
  float* out = (float*)d_out;
  float* ws  = (float*)d_ws;

  init_kernel<<<1, 256, 0, stream>>>(cinit, ws);
  for (int iter = 0; iter < 3; ++iter) {
    pass_kernel<<<NBATCH * 256, 256, 0, stream>>>(F, ws, out, iter);
    finalize_kernel<<<1, 512, 0, stream>>>(ws, out);
  }
}